// Round 7
// baseline (265.717 us; speedup 1.0000x reference)
//
#include <hip/hip_runtime.h>
#include <hip/hip_fp16.h>
#include <hip/hip_bf16.h>
#include <cmath>

#define G_NUM 128
#define NPTS  128
#define FDIM  128
#define KNNK  24
#define NTOT  (G_NUM*NPTS)   // 16384

typedef short s8v __attribute__((ext_vector_type(8)));   // 8 bf16 (4 VGPRs)
typedef float f32x4 __attribute__((ext_vector_type(4))); // MFMA accumulator

__device__ __forceinline__ float eluf(float x){ return x > 0.0f ? x : expm1f(x); }

__device__ __forceinline__ unsigned short f2bf(float f) {
    unsigned int u = __float_as_uint(f);
    unsigned int r = (u + 0x7fffu + ((u >> 16) & 1u)) >> 16;   // RNE
    return (unsigned short)r;
}
__device__ __forceinline__ float bf2f(unsigned short b) {
    return __uint_as_float(((unsigned int)b) << 16);
}

// ---------------------------------------------------------------------------
// prep: wcatT[l][n][k] bf16 (n<128: Wtop-Wbot col, else Wbot col), enc2T[n][k]
// bf16, bias[l][256] f32. Also writes batch_pf -> out[768..].
// ---------------------------------------------------------------------------
__global__ void prep_kernel(const float* __restrict__ w1, const float* __restrict__ w2,
                            const float* __restrict__ w3, const float* __restrict__ ew2,
                            const float* __restrict__ b1, const float* __restrict__ b2,
                            const float* __restrict__ b3,
                            unsigned short* __restrict__ wcatT,
                            unsigned short* __restrict__ enc2T,
                            float* __restrict__ bias,
                            const int* __restrict__ bpf,
                            float* __restrict__ out)
{
    int e = blockIdx.x * 256 + threadIdx.x;
    if (e < 16384) out[768 + e] = (float)bpf[e];
    if (e < 98304) {                       // 3 * 128k * 256n
        int l = e >> 15;
        int r = e & 32767;
        int k = r >> 8;                    // 0..127
        int n = r & 255;                   // 0..255
        const float* w = (l == 0) ? w1 : ((l == 1) ? w2 : w3);
        float v = (n < 128) ? (w[k * 128 + n] - w[(128 + k) * 128 + n])
                            : w[(128 + k) * 128 + (n - 128)];
        wcatT[l * 32768 + n * 128 + k] = f2bf(v);
    } else if (e < 114688) {               // enc2T: 128k * 128n
        int i = e - 98304;
        int k = i >> 7, n = i & 127;
        enc2T[n * 128 + k] = f2bf(ew2[k * 128 + n]);
    } else if (e < 115456) {
        int j = e - 114688;
        int l = j >> 8, c = j & 255;
        const float* b = (l == 0) ? b1 : ((l == 1) ? b2 : b3);
        bias[l * 256 + c] = (c < 128) ? b[c] : 0.0f;
    }
}

// ---------------------------------------------------------------------------
// enc_fused: 256 blocks x 512 thr, 64 rows each. enc1 fp32 VALU -> bf16 ->
// enc2 MFMA -> elu -> h f32.  (unchanged r6)
// ---------------------------------------------------------------------------
#define E_XS  0
#define E_W1  4352
#define E_A   12544
__global__ __launch_bounds__(512) void enc_fused(const float* __restrict__ x_pf,
                                                 const float* __restrict__ w1,
                                                 const float* __restrict__ b1,
                                                 const unsigned short* __restrict__ e2T,
                                                 const float* __restrict__ b2,
                                                 float* __restrict__ hout)
{
    __shared__ char smc[28928];
    float* xs  = (float*)(smc + E_XS);
    float* ws1 = (float*)(smc + E_W1);
    const int tid = threadIdx.x;
    const int m0 = blockIdx.x * 64;

    for (int e = tid; e < 1024; e += 512) {
        int m = e >> 4, k = e & 15;
        xs[m * 17 + k] = x_pf[(size_t)(m0 + m) * 16 + k];
    }
    for (int e = tid; e < 2048; e += 512) ws1[e] = w1[e];
    __syncthreads();

    {
        const int h = tid & 127, mg = tid >> 7;
        float bb = b1[h];
        #pragma unroll
        for (int i = 0; i < 16; ++i) {
            int m = mg * 16 + i;
            float a = bb;
            #pragma unroll
            for (int k = 0; k < 16; ++k) a += xs[m * 17 + k] * ws1[k * 128 + h];
            a = eluf(a);
            int byte = (m * 256 + h * 2) ^ ((m & 15) << 4);
            *reinterpret_cast<unsigned short*>(smc + E_A + byte) = f2bf(a);
        }
    }
    __syncthreads();

    {
        const int l = tid & 63, w = tid >> 6;
        const int lr = l & 15, lg = l >> 4;
        const int mt = w >> 1, nh = w & 1;
        f32x4 acc[4] = {};
        #pragma unroll
        for (int ks = 0; ks < 4; ++ks) {
            int row = mt * 16 + lr;
            int abyte = (row * 256 + ks * 64 + lg * 16) ^ ((row & 15) << 4);
            s8v a_f = *reinterpret_cast<const s8v*>(smc + E_A + abyte);
            #pragma unroll
            for (int ni = 0; ni < 4; ++ni) {
                int n = nh * 64 + ni * 16 + lr;
                s8v b = *reinterpret_cast<const s8v*>(e2T + n * 128 + ks * 32 + lg * 8);
                acc[ni] = __builtin_amdgcn_mfma_f32_16x16x32_bf16(a_f, b, acc[ni], 0, 0, 0);
            }
        }
        #pragma unroll
        for (int ni = 0; ni < 4; ++ni) {
            int n = nh * 64 + ni * 16 + lr;
            float bl = b2[n];
            #pragma unroll
            for (int q = 0; q < 4; ++q)
                hout[(size_t)(m0 + mt * 16 + lg * 4 + q) * 128 + n] = eluf(acc[ni][q] + bl);
        }
    }
}

// ---------------------------------------------------------------------------
// cgemm: per conv layer. A = h (fp32 -> bf16 staged), B = wcatT (bf16, pre-T).
// blockIdx.y==0: a = A@Wcat[:,0:128] + bias  -> f32.
// blockIdx.y==1: c = A@Wcat[:,128:256]       -> f16x2-packed uint [row][64].
// BM=128, 64KB LDS, 2 blocks/CU.
// ---------------------------------------------------------------------------
__global__ __launch_bounds__(256) void cgemm(const float* __restrict__ A,
                                             const unsigned short* __restrict__ Bt,
                                             const float* __restrict__ bias,
                                             float* __restrict__ a_out,
                                             unsigned int* __restrict__ c16)
{
    extern __shared__ char smc[];
    const int tid = threadIdx.x;
    const int m0 = blockIdx.x * 128;
    const unsigned short* Btg = Bt + (size_t)blockIdx.y * 16384;

    for (int e = tid; e < 4096; e += 256) {
        int m = e >> 5, q = e & 31;
        float4 v = *reinterpret_cast<const float4*>(&A[(size_t)(m0 + m) * 128 + 4 * q]);
        ushort4 p;
        p.x = f2bf(v.x); p.y = f2bf(v.y); p.z = f2bf(v.z); p.w = f2bf(v.w);
        int byte = (m * 256 + q * 8) ^ ((m & 15) << 4);
        *reinterpret_cast<ushort4*>(smc + byte) = p;
    }
    for (int e = tid; e < 2048; e += 256) {
        int n = e >> 4, q = e & 15;
        uint4 v = *reinterpret_cast<const uint4*>(Btg + n * 128 + q * 8);
        int byte = (n * 256 + q * 16) ^ ((n & 15) << 4);
        *reinterpret_cast<uint4*>(smc + 32768 + byte) = v;
    }
    __syncthreads();

    const int l = tid & 63, w = tid >> 6;
    const int wr = w >> 1, wc = w & 1;
    const int lr = l & 15, lg = l >> 4;

    f32x4 acc[4][4] = {};
    #pragma unroll
    for (int ks = 0; ks < 4; ++ks) {
        s8v a_f[4], b_f[4];
        #pragma unroll
        for (int mi = 0; mi < 4; ++mi) {
            int row = wr * 64 + mi * 16 + lr;
            int byte = (row * 256 + ks * 64 + lg * 16) ^ ((row & 15) << 4);
            a_f[mi] = *reinterpret_cast<const s8v*>(smc + byte);
        }
        #pragma unroll
        for (int ni = 0; ni < 4; ++ni) {
            int n = wc * 64 + ni * 16 + lr;
            int byte = (n * 256 + ks * 64 + lg * 16) ^ ((n & 15) << 4);
            b_f[ni] = *reinterpret_cast<const s8v*>(smc + 32768 + byte);
        }
        #pragma unroll
        for (int mi = 0; mi < 4; ++mi)
            #pragma unroll
            for (int ni = 0; ni < 4; ++ni)
                acc[mi][ni] = __builtin_amdgcn_mfma_f32_16x16x32_bf16(
                    a_f[mi], b_f[ni], acc[mi][ni], 0, 0, 0);
    }

    if (blockIdx.y == 0) {
        float bl[4];
        #pragma unroll
        for (int ni = 0; ni < 4; ++ni) bl[ni] = bias[wc * 64 + ni * 16 + lr];
        #pragma unroll
        for (int mi = 0; mi < 4; ++mi) {
            int rbase = m0 + wr * 64 + mi * 16 + lg * 4;
            #pragma unroll
            for (int ni = 0; ni < 4; ++ni) {
                int col = wc * 64 + ni * 16 + lr;
                #pragma unroll
                for (int q = 0; q < 4; ++q)
                    a_out[(size_t)(rbase + q) * 128 + col] = acc[mi][ni][q] + bl[ni];
            }
        }
    } else {
        #pragma unroll
        for (int mi = 0; mi < 4; ++mi) {
            int rbase = m0 + wr * 64 + mi * 16 + lg * 4;
            #pragma unroll
            for (int ni = 0; ni < 4; ++ni) {
                int col = wc * 64 + ni * 16 + lr;
                #pragma unroll
                for (int q = 0; q < 4; ++q) {
                    float v = acc[mi][ni][q];
                    float p = __shfl_xor(v, 1);
                    if (!(lr & 1)) {
                        unsigned int u =
                            ((unsigned int)__half_as_ushort(__float2half(p)) << 16)
                          |  (unsigned int)__half_as_ushort(__float2half(v));
                        c16[(size_t)(rbase + q) * 64 + (col >> 1)] = u;
                    }
                }
            }
        }
    }
}

// ---------------------------------------------------------------------------
// conv_fused v3: 512 blocks x 512 thr (8 waves), 4 blocks/graph (32 rows),
// 66 KB LDS -> 2 blocks/CU.
//  P1: stage X -> Xhi/Xlo bf16 (swizzled) + Sq.
//  d2: all 8 waves, split-bf16 MFMA, acc in regs; B2; D (16K, XOR-swz)
//      overlays dead Xlo; B3.
//  select: wave w owns rows w*4..w*4+3 (same as combine) -> idx u8 [32][24].
//  combine: elu(a_global + max_t c16_global[idx]) -> hout / pooled partial.
// LDS: Xhi 32K | Xlo 32K (-> D 16K @+0, pp 8K @+16K, idx 768 @+24K) | Sq 512
//      = 66048 B
// ---------------------------------------------------------------------------
#define CV_XHI 0
#define CV_XLO 32768
#define CV_D   32768
#define CV_PP  (32768 + 16384)
#define CV_IDX (32768 + 24576)
#define CV_SQ  65536
#define CONV_LDS 66048

template<int POOL>
__global__ __launch_bounds__(512, 4) void conv_fused(const float* __restrict__ hin,
                                                     const float* __restrict__ a_buf,
                                                     const unsigned int* __restrict__ c16,
                                                     float* __restrict__ hout,
                                                     float* __restrict__ ppool)
{
    extern __shared__ char smc[];
    float* Sq = (float*)(smc + CV_SQ);                    // [128]
    unsigned char* idxL = (unsigned char*)(smc + CV_IDX); // [32][24]
    float* pp = (float*)(smc + CV_PP);                    // [16][128]

    // 4 blocks of a graph share blockIdx%8 -> same XCD L2 slice
    const int bid = blockIdx.x;
    const int g   = (bid & 7) * 16 + (bid >> 5);
    const int sub = (bid >> 3) & 3;
    const int r0  = sub * 32;
    const int tid = threadIdx.x;
    const float* hg = hin + (size_t)g * NPTS * FDIM;
    float* og = hout + (size_t)g * NPTS * FDIM;

    // ---- P1: split-stage X (full graph) + Sq ----
    {
        const int m = tid >> 2;            // 0..127
        const int k0 = (tid & 3) * 32;
        float sq = 0.f;
        #pragma unroll
        for (int i = 0; i < 8; ++i) {
            float4 v = *reinterpret_cast<const float4*>(&hg[m * 128 + k0 + 4 * i]);
            ushort4 hi, lo;
            hi.x = f2bf(v.x); lo.x = f2bf(v.x - bf2f(hi.x));
            hi.y = f2bf(v.y); lo.y = f2bf(v.y - bf2f(hi.y));
            hi.z = f2bf(v.z); lo.z = f2bf(v.z - bf2f(hi.z));
            hi.w = f2bf(v.w); lo.w = f2bf(v.w - bf2f(hi.w));
            sq += v.x * v.x + v.y * v.y + v.z * v.z + v.w * v.w;
            int byte = (m * 256 + (k0 + 4 * i) * 2) ^ ((m & 15) << 4);
            *reinterpret_cast<ushort4*>(smc + CV_XHI + byte) = hi;
            *reinterpret_cast<ushort4*>(smc + CV_XLO + byte) = lo;
        }
        sq += __shfl_xor(sq, 1);
        sq += __shfl_xor(sq, 2);
        if ((tid & 3) == 0) Sq[m] = sq;
    }
    __syncthreads();   // B1

    const int l = tid & 63, w = tid >> 6;
    const int lr = l & 15, lg = l >> 4;

    // ---- d2 (all 8 waves): rows tile rt=w&1 (own 32), col tiles {w>>1, 4+(w>>1)} ----
    f32x4 acc[2] = {};
    const int rt = w & 1, ct0 = w >> 1;
    const int arow = r0 + rt * 16 + lr;
    const int aswz = (arow & 15) << 4;
    #pragma unroll
    for (int ks = 0; ks < 4; ++ks) {
        int abyte = (arow * 256 + ks * 64 + lg * 16) ^ aswz;
        s8v ahi = *reinterpret_cast<const s8v*>(smc + CV_XHI + abyte);
        s8v alo = *reinterpret_cast<const s8v*>(smc + CV_XLO + abyte);
        #pragma unroll
        for (int t = 0; t < 2; ++t) {
            int brow = (ct0 + 4 * t) * 16 + lr;
            int bbyte = (brow * 256 + ks * 64 + lg * 16) ^ ((brow & 15) << 4);
            s8v bhi = *reinterpret_cast<const s8v*>(smc + CV_XHI + bbyte);
            s8v blo = *reinterpret_cast<const s8v*>(smc + CV_XLO + bbyte);
            acc[t] = __builtin_amdgcn_mfma_f32_16x16x32_bf16(alo, bhi, acc[t], 0, 0, 0);
            acc[t] = __builtin_amdgcn_mfma_f32_16x16x32_bf16(ahi, blo, acc[t], 0, 0, 0);
            acc[t] = __builtin_amdgcn_mfma_f32_16x16x32_bf16(ahi, bhi, acc[t], 0, 0, 0);
        }
    }
    float sqa[4], sqc[2];
    #pragma unroll
    for (int q = 0; q < 4; ++q) sqa[q] = Sq[r0 + rt * 16 + lg * 4 + q];
    #pragma unroll
    for (int t = 0; t < 2; ++t) sqc[t] = Sq[(ct0 + 4 * t) * 16 + lr];
    __syncthreads();   // B2: all Xlo reads complete; D may overlay

    #pragma unroll
    for (int t = 0; t < 2; ++t) {
        int col = (ct0 + 4 * t) * 16 + lr;
        #pragma unroll
        for (int q = 0; q < 4; ++q) {
            int row = rt * 16 + lg * 4 + q;   // block-local 0..31
            *reinterpret_cast<float*>(smc + CV_D + ((row * 512 + col * 4) ^ ((row & 7) << 4)))
                = sqa[q] + sqc[t] - 2.f * acc[t][q];
        }
    }
    __syncthreads();   // B3

    // ---- select: wave w -> rows w*4..w*4+3 (radix top-24, exact tie rule) ----
    for (int r = w * 4; r < w * 4 + 4; ++r) {
        float2 cur = *reinterpret_cast<const float2*>(
            smc + CV_D + ((r * 512 + 8 * l) ^ ((r & 7) << 4)));
        unsigned int ub0 = __float_as_uint(cur.x);
        unsigned int ub1 = __float_as_uint(cur.y);
        unsigned int u0 = (ub0 & 0x80000000u) ? ~ub0 : (ub0 | 0x80000000u);
        unsigned int u1 = (ub1 & 0x80000000u) ? ~ub1 : (ub1 | 0x80000000u);

        bool c0 = true, c1 = true, in0 = false, in1 = false;
        int need = KNNK;
        for (int b = 31; b >= 0; --b) {
            bool z0 = c0 && !((u0 >> b) & 1u);
            bool z1 = c1 && !((u1 >> b) & 1u);
            int cnt = __popcll(__ballot(z0)) + __popcll(__ballot(z1));
            if (cnt > need) { c0 = z0; c1 = z1; }
            else if (cnt == need) { in0 |= z0; in1 |= z1; need = 0; break; }
            else { in0 |= z0; in1 |= z1; need -= cnt;
                   c0 = c0 && !z0; c1 = c1 && !z1; }
        }
        if (need > 0) {
            unsigned long long m0 = __ballot(c0), m1 = __ballot(c1);
            unsigned long long below = (1ull << l) - 1ull;
            int rk0 = __popcll(m0 & below) + __popcll(m1 & below);
            int rk1 = rk0 + (int)((m0 >> l) & 1ull);
            in0 = in0 || (c0 && rk0 < need);
            in1 = in1 || (c1 && rk1 < need);
        }
        unsigned long long f0 = __ballot(in0), f1 = __ballot(in1);
        int cnt0 = __popcll(f0);
        unsigned long long below = (1ull << l) - 1ull;
        if (in0) idxL[r * KNNK + __popcll(f0 & below)] = (unsigned char)(2 * l);
        if (in1) idxL[r * KNNK + cnt0 + __popcll(f1 & below)] = (unsigned char)(2 * l + 1);
    }
    // idx produced and consumed by the same wave: no barrier needed.

    // ---- combine: elu(a + max_t c[idx]) ----
    {
        const int hh = l >> 5, jl = l & 31;
        const float* ag = a_buf + ((size_t)g * 128 + r0) * 128;
        const unsigned int* cg = c16 + (size_t)g * 128 * 64;
        float4 ps = {0.f, 0.f, 0.f, 0.f};
        #pragma unroll
        for (int u = 0; u < 2; ++u) {
            const int r = w * 4 + 2 * u + hh;
            const unsigned char* il = &idxL[r * KNNK];
            float4 av = *reinterpret_cast<const float4*>(&ag[r * 128 + 4 * jl]);
            float mc0 = -3.0e38f, mc1 = -3.0e38f, mc2 = -3.0e38f, mc3 = -3.0e38f;
            #pragma unroll
            for (int t = 0; t < KNNK; t += 4) {
                int p0 = il[t], p1 = il[t + 1], p2 = il[t + 2], p3 = il[t + 3];
                uint2 a = *reinterpret_cast<const uint2*>(&cg[(size_t)p0 * 64 + 2 * jl]);
                uint2 b = *reinterpret_cast<const uint2*>(&cg[(size_t)p1 * 64 + 2 * jl]);
                uint2 c = *reinterpret_cast<const uint2*>(&cg[(size_t)p2 * 64 + 2 * jl]);
                uint2 d = *reinterpret_cast<const uint2*>(&cg[(size_t)p3 * 64 + 2 * jl]);
                mc0 = fmaxf(fmaxf(mc0,
                        __half2float(__ushort_as_half((unsigned short)(a.x & 0xffffu)))),
                        fmaxf(__half2float(__ushort_as_half((unsigned short)(b.x & 0xffffu))),
                              fmaxf(__half2float(__ushort_as_half((unsigned short)(c.x & 0xffffu))),
                                    __half2float(__ushort_as_half((unsigned short)(d.x & 0xffffu))))));
                mc1 = fmaxf(fmaxf(mc1,
                        __half2float(__ushort_as_half((unsigned short)(a.x >> 16)))),
                        fmaxf(__half2float(__ushort_as_half((unsigned short)(b.x >> 16))),
                              fmaxf(__half2float(__ushort_as_half((unsigned short)(c.x >> 16))),
                                    __half2float(__ushort_as_half((unsigned short)(d.x >> 16))))));
                mc2 = fmaxf(fmaxf(mc2,
                        __half2float(__ushort_as_half((unsigned short)(a.y & 0xffffu)))),
                        fmaxf(__half2float(__ushort_as_half((unsigned short)(b.y & 0xffffu))),
                              fmaxf(__half2float(__ushort_as_half((unsigned short)(c.y & 0xffffu))),
                                    __half2float(__ushort_as_half((unsigned short)(d.y & 0xffffu))))));
                mc3 = fmaxf(fmaxf(mc3,
                        __half2float(__ushort_as_half((unsigned short)(a.y >> 16)))),
                        fmaxf(__half2float(__ushort_as_half((unsigned short)(b.y >> 16))),
                              fmaxf(__half2float(__ushort_as_half((unsigned short)(c.y >> 16))),
                                    __half2float(__ushort_as_half((unsigned short)(d.y >> 16))))));
            }
            float4 o;
            o.x = eluf(av.x + mc0);
            o.y = eluf(av.y + mc1);
            o.z = eluf(av.z + mc2);
            o.w = eluf(av.w + mc3);
            if (!POOL) {
                *reinterpret_cast<float4*>(&og[(r0 + r) * 128 + 4 * jl]) = o;
            } else {
                ps.x += o.x; ps.y += o.y; ps.z += o.z; ps.w += o.w;
            }
        }
        if (POOL) {
            *reinterpret_cast<float4*>(&pp[(w * 2 + hh) * 128 + 4 * jl]) = ps;
            __syncthreads();
            if (tid < 128) {
                float s = 0.f;
                #pragma unroll 8
                for (int rg = 0; rg < 16; ++rg) s += pp[rg * 128 + tid];
                ppool[(size_t)(g * 4 + sub) * 128 + tid] = s;
            }
        }
    }
}

// ---------------------------------------------------------------------------
// head: sums 4 pooled partials per graph + 128->64->32->32->6 MLP
// ---------------------------------------------------------------------------
__global__ __launch_bounds__(128) void head_kernel(const float* __restrict__ ppool,
        const float* __restrict__ w1, const float* __restrict__ b1,
        const float* __restrict__ w2, const float* __restrict__ b2,
        const float* __restrict__ w3, const float* __restrict__ b3,
        const float* __restrict__ w4, const float* __restrict__ b4,
        float* __restrict__ out)
{
    __shared__ float pooled[128], s1[64], s2[32], s3[32];
    const int g = blockIdx.x, t = threadIdx.x;
    pooled[t] = ppool[(size_t)(4 * g) * 128 + t] + ppool[(size_t)(4 * g + 1) * 128 + t]
              + ppool[(size_t)(4 * g + 2) * 128 + t] + ppool[(size_t)(4 * g + 3) * 128 + t];
    __syncthreads();
    if (t < 64) {
        float a = b1[t];
        #pragma unroll 8
        for (int k = 0; k < 128; ++k) a += pooled[k] * w1[k * 64 + t];
        s1[t] = eluf(a);
    }
    __syncthreads();
    if (t < 32) {
        float a = b2[t];
        #pragma unroll 8
        for (int k = 0; k < 64; ++k) a += s1[k] * w2[k * 32 + t];
        s2[t] = eluf(a);
    }
    __syncthreads();
    if (t < 32) {
        float a = b3[t];
        #pragma unroll 8
        for (int k = 0; k < 32; ++k) a += s2[k] * w3[k * 32 + t];
        s3[t] = eluf(a);
    }
    __syncthreads();
    if (t < 6) {
        float a = b4[t];
        #pragma unroll 8
        for (int k = 0; k < 32; ++k) a += s3[k] * w4[k * 6 + t];
        out[g * 6 + t] = a;
    }
}

// ---------------------------------------------------------------------------
extern "C" void kernel_launch(void* const* d_in, const int* in_sizes, int n_in,
                              void* d_out, int out_size, void* d_ws, size_t ws_size,
                              hipStream_t stream)
{
    const float* x_pf   = (const float*)d_in[0];
    const float* enc_w1 = (const float*)d_in[1];
    const float* enc_b1 = (const float*)d_in[2];
    const float* enc_w2 = (const float*)d_in[3];
    const float* enc_b2 = (const float*)d_in[4];
    const float* c1w = (const float*)d_in[5];
    const float* c1b = (const float*)d_in[6];
    const float* c2w = (const float*)d_in[7];
    const float* c2b = (const float*)d_in[8];
    const float* c3w = (const float*)d_in[9];
    const float* c3b = (const float*)d_in[10];
    const float* o_w1 = (const float*)d_in[11];
    const float* o_b1 = (const float*)d_in[12];
    const float* o_w2 = (const float*)d_in[13];
    const float* o_b2 = (const float*)d_in[14];
    const float* o_w3 = (const float*)d_in[15];
    const float* o_b3 = (const float*)d_in[16];
    const float* o_w4 = (const float*)d_in[17];
    const float* o_b4 = (const float*)d_in[18];
    const int*   bpf  = (const int*)d_in[19];
    float* out = (float*)d_out;

    float* ws    = (float*)d_ws;
    float* h_a   = ws;                              // 16384*128 f32
    float* h_b   = h_a + (size_t)NTOT * FDIM;       // 16384*128 f32
    float* a_buf = h_b + (size_t)NTOT * FDIM;       // 16384*128 f32
    unsigned int* c16 = (unsigned int*)(a_buf + (size_t)NTOT * FDIM); // 16384*64 u32
    float* ppool = (float*)(c16 + (size_t)NTOT * 64);                 // 512*128 f32
    unsigned short* wcatT = (unsigned short*)(ppool + 512 * 128);     // 3*256*128 bf16
    unsigned short* enc2T = wcatT + 3 * 32768;      // 128*128 bf16
    float* biasF = (float*)(enc2T + 16384);         // 3*256 f32

    prep_kernel<<<451, 256, 0, stream>>>(c1w, c2w, c3w, enc_w2,
                                         c1b, c2b, c3b, wcatT, enc2T, biasF,
                                         bpf, out);

    enc_fused<<<NTOT / 64, 512, 0, stream>>>(x_pf, enc_w1, enc_b1,
                                             enc2T, enc_b2, h_a);

    float* hc = h_a;
    float* hn = h_b;
    for (int lyr = 0; lyr < 3; ++lyr) {
        cgemm<<<dim3(NTOT / 128, 2), 256, 65536, stream>>>(
            hc, wcatT + (size_t)lyr * 32768, biasF + lyr * 256, a_buf, c16);
        if (lyr < 2)
            conv_fused<0><<<512, 512, CONV_LDS, stream>>>(hc, a_buf, c16, hn, ppool);
        else
            conv_fused<1><<<512, 512, CONV_LDS, stream>>>(hc, a_buf, c16, hn, ppool);
        float* t = hc; hc = hn; hn = t;
    }

    head_kernel<<<G_NUM, 128, 0, stream>>>(ppool, o_w1, o_b1, o_w2, o_b2,
                                           o_w3, o_b3, o_w4, o_b4, out);
}

// Round 9
// 261.309 us; speedup vs baseline: 1.0169x; 1.0169x over previous
//
#include <hip/hip_runtime.h>
#include <hip/hip_fp16.h>
#include <cmath>

#define G_NUM 128
#define NPTS  128
#define FDIM  128
#define KNNK  24
#define NTOT  (G_NUM*NPTS)   // 16384

typedef short s8v __attribute__((ext_vector_type(8)));   // 8 bf16 (4 VGPRs)
typedef float f32x4 __attribute__((ext_vector_type(4))); // MFMA accumulator

__device__ __forceinline__ float eluf(float x){ return x > 0.0f ? x : expm1f(x); }

__device__ __forceinline__ unsigned short f2bf(float f) {
    unsigned int u = __float_as_uint(f);
    unsigned int r = (u + 0x7fffu + ((u >> 16) & 1u)) >> 16;   // RNE
    return (unsigned short)r;
}
__device__ __forceinline__ float bf2f(unsigned short b) {
    return __uint_as_float(((unsigned int)b) << 16);
}
__device__ __forceinline__ unsigned short f2h(float f){ return __half_as_ushort(__float2half(f)); }
__device__ __forceinline__ float h2f(unsigned short h){ return __half2float(__ushort_as_half(h)); }

// ---------------------------------------------------------------------------
// prep: wcatT[l][n][k] bf16 (n<128: Wtop-Wbot col, else Wbot col), enc2T[n][k]
// bf16, bias[l][256] f32. Also writes batch_pf -> out[768..].
// ---------------------------------------------------------------------------
__global__ void prep_kernel(const float* __restrict__ w1, const float* __restrict__ w2,
                            const float* __restrict__ w3, const float* __restrict__ ew2,
                            const float* __restrict__ b1, const float* __restrict__ b2,
                            const float* __restrict__ b3,
                            unsigned short* __restrict__ wcatT,
                            unsigned short* __restrict__ enc2T,
                            float* __restrict__ bias,
                            const int* __restrict__ bpf,
                            float* __restrict__ out)
{
    int e = blockIdx.x * 256 + threadIdx.x;
    if (e < 16384) out[768 + e] = (float)bpf[e];
    if (e < 98304) {                       // 3 * 128k * 256n
        int l = e >> 15;
        int r = e & 32767;
        int k = r >> 8;                    // 0..127
        int n = r & 255;                   // 0..255
        const float* w = (l == 0) ? w1 : ((l == 1) ? w2 : w3);
        float v = (n < 128) ? (w[k * 128 + n] - w[(128 + k) * 128 + n])
                            : w[(128 + k) * 128 + (n - 128)];
        wcatT[l * 32768 + n * 128 + k] = f2bf(v);
    } else if (e < 114688) {               // enc2T: 128k * 128n
        int i = e - 98304;
        int k = i >> 7, n = i & 127;
        enc2T[n * 128 + k] = f2bf(ew2[k * 128 + n]);
    } else if (e < 115456) {
        int j = e - 114688;
        int l = j >> 8, c = j & 255;
        const float* b = (l == 0) ? b1 : ((l == 1) ? b2 : b3);
        bias[l * 256 + c] = (c < 128) ? b[c] : 0.0f;
    }
}

// ---------------------------------------------------------------------------
// enc_fused: 256 blocks x 512 thr, 64 rows each. enc1 fp32 VALU -> bf16 ->
// enc2 MFMA -> elu -> h f32.  (r7-proven)
// ---------------------------------------------------------------------------
#define E_XS  0
#define E_W1  4352
#define E_A   12544
__global__ __launch_bounds__(512) void enc_fused(const float* __restrict__ x_pf,
                                                 const float* __restrict__ w1,
                                                 const float* __restrict__ b1,
                                                 const unsigned short* __restrict__ e2T,
                                                 const float* __restrict__ b2,
                                                 float* __restrict__ hout)
{
    __shared__ char smc[28928];
    float* xs  = (float*)(smc + E_XS);
    float* ws1 = (float*)(smc + E_W1);
    const int tid = threadIdx.x;
    const int m0 = blockIdx.x * 64;

    for (int e = tid; e < 1024; e += 512) {
        int m = e >> 4, k = e & 15;
        xs[m * 17 + k] = x_pf[(size_t)(m0 + m) * 16 + k];
    }
    for (int e = tid; e < 2048; e += 512) ws1[e] = w1[e];
    __syncthreads();

    {
        const int h = tid & 127, mg = tid >> 7;
        float bb = b1[h];
        #pragma unroll
        for (int i = 0; i < 16; ++i) {
            int m = mg * 16 + i;
            float a = bb;
            #pragma unroll
            for (int k = 0; k < 16; ++k) a += xs[m * 17 + k] * ws1[k * 128 + h];
            a = eluf(a);
            int byte = (m * 256 + h * 2) ^ ((m & 15) << 4);
            *reinterpret_cast<unsigned short*>(smc + E_A + byte) = f2bf(a);
        }
    }
    __syncthreads();

    {
        const int l = tid & 63, w = tid >> 6;
        const int lr = l & 15, lg = l >> 4;
        const int mt = w >> 1, nh = w & 1;
        f32x4 acc[4] = {};
        #pragma unroll
        for (int ks = 0; ks < 4; ++ks) {
            int row = mt * 16 + lr;
            int abyte = (row * 256 + ks * 64 + lg * 16) ^ ((row & 15) << 4);
            s8v a_f = *reinterpret_cast<const s8v*>(smc + E_A + abyte);
            #pragma unroll
            for (int ni = 0; ni < 4; ++ni) {
                int n = nh * 64 + ni * 16 + lr;
                s8v b = *reinterpret_cast<const s8v*>(e2T + n * 128 + ks * 32 + lg * 8);
                acc[ni] = __builtin_amdgcn_mfma_f32_16x16x32_bf16(a_f, b, acc[ni], 0, 0, 0);
            }
        }
        #pragma unroll
        for (int ni = 0; ni < 4; ++ni) {
            int n = nh * 64 + ni * 16 + lr;
            float bl = b2[n];
            #pragma unroll
            for (int q = 0; q < 4; ++q)
                hout[(size_t)(m0 + mt * 16 + lg * 4 + q) * 128 + n] = eluf(acc[ni][q] + bl);
        }
    }
}

// ---------------------------------------------------------------------------
// conv_all: full DynamicEdgeConv layer, one kernel. 512 blocks x 512 thr
// (4 blocks/graph, 32 own rows), 66.8 KB LDS -> 2 blocks/CU.
//  P1: split-stage X (hi/lo bf16, swizzled) + Sq.
//  P2: waves 0-3: d2 split-bf16 MFMA (own 32 rows x 128) -> regs;
//      waves 4-7: c-GEMM (all 128 rows, B from global wcatT) -> f16x2 -> c16,
//                 then a-GEMM (own 32 rows) + bias -> f16x2 -> a16.
//  B2; waves 0-3 write D (16K, XOR-swz, overlays Xlo lower half); B3.
//  select: wave w -> rows w*4..w*4+3 (radix top-24, exact tie) -> idx u8.
//  combine: elu(a16 + max_t c16[idx]) -> hout f32 / pooled partial.
// LDS: Xhi 32K | Xlo 32K (-> D 16K @32768, pp 8K @49152) | idx 1.5K | Sq 0.5K
// ---------------------------------------------------------------------------
#define CV_XHI 0
#define CV_XLO 32768
#define CV_D   32768
#define CV_PP  49152
#define CV_IDX 65536
#define CV_SQ  66304
#define CONV_LDS 66816

template<int POOL>
__global__ __launch_bounds__(512, 4) void conv_all(const float* __restrict__ hin,
                                                   const unsigned short* __restrict__ wT,
                                                   const float* __restrict__ bias,
                                                   float* __restrict__ hout,
                                                   unsigned int* __restrict__ a16,
                                                   unsigned int* __restrict__ c16,
                                                   float* __restrict__ ppool)
{
    extern __shared__ char smc[];
    float* Sq = (float*)(smc + CV_SQ);                    // [128]
    unsigned char* idxL = (unsigned char*)(smc + CV_IDX); // [32][24]
    float* pp = (float*)(smc + CV_PP);                    // [16][128]

    // 4 blocks of a graph share bid%8 -> same XCD L2 slice
    const int bid = blockIdx.x;
    const int g   = (bid & 7) | ((bid >> 5) << 3);
    const int sub = (bid >> 3) & 3;
    const int r0  = sub * 32;
    const int tid = threadIdx.x;
    const float* hg = hin + (size_t)g * NPTS * FDIM;
    unsigned int* a16g = a16 + (size_t)g * NPTS * 64;
    unsigned int* c16g = c16 + (size_t)g * NPTS * 64;

    // ---- P1: split-stage X (full graph) + Sq ----
    {
        const int m = tid >> 2;            // 0..127
        const int k0 = (tid & 3) * 32;
        float sq = 0.f;
        #pragma unroll
        for (int i = 0; i < 8; ++i) {
            float4 v = *reinterpret_cast<const float4*>(&hg[m * 128 + k0 + 4 * i]);
            ushort4 hi, lo;
            hi.x = f2bf(v.x); lo.x = f2bf(v.x - bf2f(hi.x));
            hi.y = f2bf(v.y); lo.y = f2bf(v.y - bf2f(hi.y));
            hi.z = f2bf(v.z); lo.z = f2bf(v.z - bf2f(hi.z));
            hi.w = f2bf(v.w); lo.w = f2bf(v.w - bf2f(hi.w));
            sq += v.x * v.x + v.y * v.y + v.z * v.z + v.w * v.w;
            int byte = (m * 256 + (k0 + 4 * i) * 2) ^ ((m & 15) << 4);
            *reinterpret_cast<ushort4*>(smc + CV_XHI + byte) = hi;
            *reinterpret_cast<ushort4*>(smc + CV_XLO + byte) = lo;
        }
        sq += __shfl_xor(sq, 1);
        sq += __shfl_xor(sq, 2);
        if ((tid & 3) == 0) Sq[m] = sq;
    }
    __syncthreads();   // B1

    const int l = tid & 63, w = tid >> 6;
    const int lr = l & 15, lg = l >> 4;

    // ---- P2: d2 (waves 0-3) || c-GEMM + a-GEMM (waves 4-7) ----
    f32x4 dacc[4] = {};
    float sqa[4], sqc[4];
    if (w < 4) {
        const int rt = w >> 1;             // own row-tile 0..1
        const int ch = w & 1;              // col half (4 tiles)
        const int arow = r0 + rt * 16 + lr;
        const int aswz = (arow & 15) << 4;
        #pragma unroll
        for (int ks = 0; ks < 4; ++ks) {
            int abyte = (arow * 256 + ks * 64 + lg * 16) ^ aswz;
            s8v ahi = *reinterpret_cast<const s8v*>(smc + CV_XHI + abyte);
            s8v alo = *reinterpret_cast<const s8v*>(smc + CV_XLO + abyte);
            #pragma unroll
            for (int t = 0; t < 4; ++t) {
                int brow = (ch * 4 + t) * 16 + lr;
                int bbyte = (brow * 256 + ks * 64 + lg * 16) ^ ((brow & 15) << 4);
                s8v bhi = *reinterpret_cast<const s8v*>(smc + CV_XHI + bbyte);
                s8v blo = *reinterpret_cast<const s8v*>(smc + CV_XLO + bbyte);
                dacc[t] = __builtin_amdgcn_mfma_f32_16x16x32_bf16(alo, bhi, dacc[t], 0, 0, 0);
                dacc[t] = __builtin_amdgcn_mfma_f32_16x16x32_bf16(ahi, blo, dacc[t], 0, 0, 0);
                dacc[t] = __builtin_amdgcn_mfma_f32_16x16x32_bf16(ahi, bhi, dacc[t], 0, 0, 0);
            }
        }
        #pragma unroll
        for (int q = 0; q < 4; ++q) sqa[q] = Sq[r0 + rt * 16 + lg * 4 + q];
        #pragma unroll
        for (int t = 0; t < 4; ++t) sqc[t] = Sq[(ch * 4 + t) * 16 + lr];
    } else {
        const int w4 = w - 4;              // 0..3
        {   // c-GEMM: row-tiles {2w4, 2w4+1} x all 8 col-tiles (cols 128..255 of wcat)
            f32x4 cacc[2][8] = {};
            #pragma unroll
            for (int ks = 0; ks < 4; ++ks) {
                s8v a_f[2];
                #pragma unroll
                for (int m2 = 0; m2 < 2; ++m2) {
                    int row = (2 * w4 + m2) * 16 + lr;
                    int byte = (row * 256 + ks * 64 + lg * 16) ^ ((row & 15) << 4);
                    a_f[m2] = *reinterpret_cast<const s8v*>(smc + CV_XHI + byte);
                }
                #pragma unroll
                for (int ni = 0; ni < 8; ++ni) {
                    int n = 128 + ni * 16 + lr;
                    s8v b = *reinterpret_cast<const s8v*>(wT + n * 128 + ks * 32 + lg * 8);
                    #pragma unroll
                    for (int m2 = 0; m2 < 2; ++m2)
                        cacc[m2][ni] = __builtin_amdgcn_mfma_f32_16x16x32_bf16(
                            a_f[m2], b, cacc[m2][ni], 0, 0, 0);
                }
            }
            #pragma unroll
            for (int m2 = 0; m2 < 2; ++m2)
                #pragma unroll
                for (int ni = 0; ni < 8; ++ni)
                    #pragma unroll
                    for (int q = 0; q < 4; ++q) {
                        float v = cacc[m2][ni][q];
                        float p = __shfl_xor(v, 1);
                        if (!(lr & 1)) {
                            unsigned int u = ((unsigned int)f2h(p) << 16) | f2h(v);
                            int j = (2 * w4 + m2) * 16 + lg * 4 + q;
                            c16g[(size_t)j * 64 + ((ni * 16 + lr) >> 1)] = u;
                        }
                    }
        }
        {   // a-GEMM: own 32 rows x col-tiles {2w4, 2w4+1}
            f32x4 aacc[2][2] = {};
            #pragma unroll
            for (int ks = 0; ks < 4; ++ks) {
                s8v a_f[2];
                #pragma unroll
                for (int m2 = 0; m2 < 2; ++m2) {
                    int row = r0 + m2 * 16 + lr;
                    int byte = (row * 256 + ks * 64 + lg * 16) ^ ((row & 15) << 4);
                    a_f[m2] = *reinterpret_cast<const s8v*>(smc + CV_XHI + byte);
                }
                #pragma unroll
                for (int ci = 0; ci < 2; ++ci) {
                    int n = (2 * w4 + ci) * 16 + lr;
                    s8v b = *reinterpret_cast<const s8v*>(wT + n * 128 + ks * 32 + lg * 8);
                    #pragma unroll
                    for (int m2 = 0; m2 < 2; ++m2)
                        aacc[m2][ci] = __builtin_amdgcn_mfma_f32_16x16x32_bf16(
                            a_f[m2], b, aacc[m2][ci], 0, 0, 0);
                }
            }
            #pragma unroll
            for (int m2 = 0; m2 < 2; ++m2)
                #pragma unroll
                for (int ci = 0; ci < 2; ++ci) {
                    int col = (2 * w4 + ci) * 16 + lr;
                    float bl = bias[col];
                    #pragma unroll
                    for (int q = 0; q < 4; ++q) {
                        float v = aacc[m2][ci][q] + bl;
                        float p = __shfl_xor(v, 1);
                        if (!(lr & 1)) {
                            unsigned int u = ((unsigned int)f2h(p) << 16) | f2h(v);
                            int row = r0 + m2 * 16 + lg * 4 + q;
                            a16g[(size_t)row * 64 + (col >> 1)] = u;
                        }
                    }
                }
        }
    }
    __syncthreads();   // B2: Xlo reads done -> D may overlay

    if (w < 4) {
        const int rt = w >> 1, ch = w & 1;
        #pragma unroll
        for (int t = 0; t < 4; ++t) {
            int col = (ch * 4 + t) * 16 + lr;
            #pragma unroll
            for (int q = 0; q < 4; ++q) {
                int row = rt * 16 + lg * 4 + q;   // block-local 0..31
                *reinterpret_cast<float*>(smc + CV_D + ((row * 512 + col * 4) ^ ((row & 7) << 4)))
                    = sqa[q] + sqc[t] - 2.f * dacc[t][q];
            }
        }
    }
    __syncthreads();   // B3

    // ---- select: wave w -> rows w*4..w*4+3 (radix top-24, exact tie rule) ----
    for (int r = w * 4; r < w * 4 + 4; ++r) {
        float2 cur = *reinterpret_cast<const float2*>(
            smc + CV_D + ((r * 512 + 8 * l) ^ ((r & 7) << 4)));
        unsigned int ub0 = __float_as_uint(cur.x);
        unsigned int ub1 = __float_as_uint(cur.y);
        unsigned int u0 = (ub0 & 0x80000000u) ? ~ub0 : (ub0 | 0x80000000u);
        unsigned int u1 = (ub1 & 0x80000000u) ? ~ub1 : (ub1 | 0x80000000u);

        bool c0 = true, c1 = true, in0 = false, in1 = false;
        int need = KNNK;
        for (int b = 31; b >= 0; --b) {
            bool z0 = c0 && !((u0 >> b) & 1u);
            bool z1 = c1 && !((u1 >> b) & 1u);
            int cnt = __popcll(__ballot(z0)) + __popcll(__ballot(z1));
            if (cnt > need) { c0 = z0; c1 = z1; }
            else if (cnt == need) { in0 |= z0; in1 |= z1; need = 0; break; }
            else { in0 |= z0; in1 |= z1; need -= cnt;
                   c0 = c0 && !z0; c1 = c1 && !z1; }
        }
        if (need > 0) {
            unsigned long long m0 = __ballot(c0), m1 = __ballot(c1);
            unsigned long long below = (1ull << l) - 1ull;
            int rk0 = __popcll(m0 & below) + __popcll(m1 & below);
            int rk1 = rk0 + (int)((m0 >> l) & 1ull);
            in0 = in0 || (c0 && rk0 < need);
            in1 = in1 || (c1 && rk1 < need);
        }
        unsigned long long f0 = __ballot(in0), f1 = __ballot(in1);
        int cnt0 = __popcll(f0);
        unsigned long long below = (1ull << l) - 1ull;
        if (in0) idxL[r * KNNK + __popcll(f0 & below)] = (unsigned char)(2 * l);
        if (in1) idxL[r * KNNK + cnt0 + __popcll(f1 & below)] = (unsigned char)(2 * l + 1);
    }
    // idx produced and consumed by the same wave: no barrier needed.

    // ---- combine: elu(a + max_t c[idx]) ----
    {
        const int hh = l >> 5, jl = l & 31;
        float* og = hout + (size_t)g * NPTS * FDIM;
        float4 ps = {0.f, 0.f, 0.f, 0.f};
        #pragma unroll
        for (int u = 0; u < 2; ++u) {
            const int r = w * 4 + 2 * u + hh;
            const unsigned char* il = &idxL[r * KNNK];
            uint2 avu = *reinterpret_cast<const uint2*>(&a16g[(size_t)(r0 + r) * 64 + 2 * jl]);
            float mc0 = -3.0e38f, mc1 = -3.0e38f, mc2 = -3.0e38f, mc3 = -3.0e38f;
            #pragma unroll
            for (int t = 0; t < KNNK; t += 4) {
                int p0 = il[t], p1 = il[t + 1], p2 = il[t + 2], p3 = il[t + 3];
                uint2 a = *reinterpret_cast<const uint2*>(&c16g[(size_t)p0 * 64 + 2 * jl]);
                uint2 b = *reinterpret_cast<const uint2*>(&c16g[(size_t)p1 * 64 + 2 * jl]);
                uint2 c = *reinterpret_cast<const uint2*>(&c16g[(size_t)p2 * 64 + 2 * jl]);
                uint2 d = *reinterpret_cast<const uint2*>(&c16g[(size_t)p3 * 64 + 2 * jl]);
                mc0 = fmaxf(fmaxf(mc0, h2f((unsigned short)(a.x & 0xffffu))),
                        fmaxf(h2f((unsigned short)(b.x & 0xffffu)),
                              fmaxf(h2f((unsigned short)(c.x & 0xffffu)),
                                    h2f((unsigned short)(d.x & 0xffffu)))));
                mc1 = fmaxf(fmaxf(mc1, h2f((unsigned short)(a.x >> 16))),
                        fmaxf(h2f((unsigned short)(b.x >> 16)),
                              fmaxf(h2f((unsigned short)(c.x >> 16)),
                                    h2f((unsigned short)(d.x >> 16)))));
                mc2 = fmaxf(fmaxf(mc2, h2f((unsigned short)(a.y & 0xffffu))),
                        fmaxf(h2f((unsigned short)(b.y & 0xffffu)),
                              fmaxf(h2f((unsigned short)(c.y & 0xffffu)),
                                    h2f((unsigned short)(d.y & 0xffffu)))));
                mc3 = fmaxf(fmaxf(mc3, h2f((unsigned short)(a.y >> 16))),
                        fmaxf(h2f((unsigned short)(b.y >> 16)),
                              fmaxf(h2f((unsigned short)(c.y >> 16)),
                                    h2f((unsigned short)(d.y >> 16)))));
            }
            float o0 = eluf(h2f((unsigned short)(avu.x & 0xffffu)) + mc0);
            float o1 = eluf(h2f((unsigned short)(avu.x >> 16)) + mc1);
            float o2 = eluf(h2f((unsigned short)(avu.y & 0xffffu)) + mc2);
            float o3 = eluf(h2f((unsigned short)(avu.y >> 16)) + mc3);
            if (!POOL) {
                float4 o = {o0, o1, o2, o3};
                *reinterpret_cast<float4*>(&og[(size_t)(r0 + r) * 128 + 4 * jl]) = o;
            } else {
                ps.x += o0; ps.y += o1; ps.z += o2; ps.w += o3;
            }
        }
        if (POOL) {
            *reinterpret_cast<float4*>(&pp[(w * 2 + hh) * 128 + 4 * jl]) = ps;
            __syncthreads();
            if (tid < 128) {
                float s = 0.f;
                #pragma unroll 8
                for (int rg = 0; rg < 16; ++rg) s += pp[rg * 128 + tid];
                ppool[(size_t)(g * 4 + sub) * 128 + tid] = s;
            }
        }
    }
}

// ---------------------------------------------------------------------------
// head: sums 4 pooled partials per graph + 128->64->32->32->6 MLP
// ---------------------------------------------------------------------------
__global__ __launch_bounds__(128) void head_kernel(const float* __restrict__ ppool,
        const float* __restrict__ w1, const float* __restrict__ b1,
        const float* __restrict__ w2, const float* __restrict__ b2,
        const float* __restrict__ w3, const float* __restrict__ b3,
        const float* __restrict__ w4, const float* __restrict__ b4,
        float* __restrict__ out)
{
    __shared__ float pooled[128], s1[64], s2[32], s3[32];
    const int g = blockIdx.x, t = threadIdx.x;
    pooled[t] = ppool[(size_t)(4 * g) * 128 + t] + ppool[(size_t)(4 * g + 1) * 128 + t]
              + ppool[(size_t)(4 * g + 2) * 128 + t] + ppool[(size_t)(4 * g + 3) * 128 + t];
    __syncthreads();
    if (t < 64) {
        float a = b1[t];
        #pragma unroll 8
        for (int k = 0; k < 128; ++k) a += pooled[k] * w1[k * 64 + t];
        s1[t] = eluf(a);
    }
    __syncthreads();
    if (t < 32) {
        float a = b2[t];
        #pragma unroll 8
        for (int k = 0; k < 64; ++k) a += s1[k] * w2[k * 32 + t];
        s2[t] = eluf(a);
    }
    __syncthreads();
    if (t < 32) {
        float a = b3[t];
        #pragma unroll 8
        for (int k = 0; k < 32; ++k) a += s2[k] * w3[k * 32 + t];
        s3[t] = eluf(a);
    }
    __syncthreads();
    if (t < 6) {
        float a = b4[t];
        #pragma unroll 8
        for (int k = 0; k < 32; ++k) a += s3[k] * w4[k * 6 + t];
        out[g * 6 + t] = a;
    }
}

// ---------------------------------------------------------------------------
extern "C" void kernel_launch(void* const* d_in, const int* in_sizes, int n_in,
                              void* d_out, int out_size, void* d_ws, size_t ws_size,
                              hipStream_t stream)
{
    const float* x_pf   = (const float*)d_in[0];
    const float* enc_w1 = (const float*)d_in[1];
    const float* enc_b1 = (const float*)d_in[2];
    const float* enc_w2 = (const float*)d_in[3];
    const float* enc_b2 = (const float*)d_in[4];
    const float* c1w = (const float*)d_in[5];
    const float* c1b = (const float*)d_in[6];
    const float* c2w = (const float*)d_in[7];
    const float* c2b = (const float*)d_in[8];
    const float* c3w = (const float*)d_in[9];
    const float* c3b = (const float*)d_in[10];
    const float* o_w1 = (const float*)d_in[11];
    const float* o_b1 = (const float*)d_in[12];
    const float* o_w2 = (const float*)d_in[13];
    const float* o_b2 = (const float*)d_in[14];
    const float* o_w3 = (const float*)d_in[15];
    const float* o_b3 = (const float*)d_in[16];
    const float* o_w4 = (const float*)d_in[17];
    const float* o_b4 = (const float*)d_in[18];
    const int*   bpf  = (const int*)d_in[19];
    float* out = (float*)d_out;

    float* h_a = (float*)d_ws;                          // NTOT*128 f32
    float* h_b = h_a + (size_t)NTOT * FDIM;             // NTOT*128 f32
    unsigned int* a16 = (unsigned int*)(h_b + (size_t)NTOT * FDIM); // NTOT*64 u32
    unsigned int* c16 = a16 + (size_t)NTOT * 64;        // NTOT*64 u32
    float* ppool = (float*)(c16 + (size_t)NTOT * 64);   // 512*128 f32
    unsigned short* wcatT = (unsigned short*)(ppool + 512 * 128); // 3*256*128 bf16
    unsigned short* enc2T = wcatT + 3 * 32768;          // 128*128 bf16
    float* biasF = (float*)(enc2T + 16384);             // 3*256 f32

    prep_kernel<<<451, 256, 0, stream>>>(c1w, c2w, c3w, enc_w2,
                                         c1b, c2b, c3b, wcatT, enc2T, biasF,
                                         bpf, out);

    enc_fused<<<NTOT / 64, 512, 0, stream>>>(x_pf, enc_w1, enc_b1,
                                             enc2T, enc_b2, h_a);

    float* hc = h_a;
    float* hn = h_b;
    for (int lyr = 0; lyr < 3; ++lyr) {
        if (lyr < 2)
            conv_all<0><<<512, 512, CONV_LDS, stream>>>(
                hc, wcatT + (size_t)lyr * 32768, biasF + lyr * 256, hn, a16, c16, ppool);
        else
            conv_all<1><<<512, 512, CONV_LDS, stream>>>(
                hc, wcatT + (size_t)lyr * 32768, biasF + lyr * 256, hn, a16, c16, ppool);
        float* t = hc; hc = hn; hn = t;
    }

    head_kernel<<<G_NUM, 128, 0, stream>>>(ppool, o_w1, o_b1, o_w2, o_b2,
                                           o_w3, o_b3, o_w4, o_b4, out);
}